// Round 1
// baseline (597.496 us; speedup 1.0000x reference)
//
#include <hip/hip_runtime.h>
#include <stdint.h>
#include <limits.h>

// WTA-LIF: (160,128,48,48) fp32. TIME_STEP=5, bs=32, P=128*48*48=294912,
// K = int(0.2*P) = 58982. Stage 1: per-sample top-K threshold via 3-pass
// radix select + exact tie cutoff (jax top_k: lower index wins ties).
// Stage 2: LIF chain over t with mask applied.

#define TSTEP 5
#define BS 32
#define P_TOT 294912
#define P4_TOT 73728      // P_TOT / 4
#define K_SEL 58982
#define VTH 1.0f
#define TAU 0.5f

struct SampleInfo { unsigned int T; int cutoff; };

// Monotonic float->uint key: bigger float <=> bigger key (NaN-free input).
__device__ __forceinline__ unsigned int f2key(float f) {
    unsigned int b = __float_as_uint(f);
    return b ^ ((unsigned int)((int)b >> 31) | 0x80000000u);
}

__global__ __launch_bounds__(1024)
void wta_select(const float4* __restrict__ x, SampleInfo* __restrict__ info)
{
    __shared__ unsigned int h1[16][1024];   // 64 KB: per-wave pass-1 histograms
    __shared__ unsigned int h2[2048];       // 8 KB: shared hist (pass1 totals / pass2 / pass3)
    __shared__ int tiebuf[2048];            // 8 KB: tie index collection
    __shared__ unsigned int sh_bin1, sh_bin2, sh_bin3, sh_r, sh_ceq, sh_cnt;
    __shared__ int sh_cutoff;

    const int s   = blockIdx.x;             // sample 0..159
    const int tid = threadIdx.x;
    const int wid = tid >> 6;               // wave 0..15
    const float4* xs = x + (size_t)s * P4_TOT;

    for (int i = tid; i < 16 * 1024; i += 1024) (&h1[0][0])[i] = 0u;
    __syncthreads();

    // ---- pass 1: top 10 bits (sign+exponent+1 mantissa bit) ----
    for (int i = tid; i < P4_TOT; i += 1024) {
        float4 v = xs[i];
        atomicAdd(&h1[wid][f2key(v.x) >> 22], 1u);
        atomicAdd(&h1[wid][f2key(v.y) >> 22], 1u);
        atomicAdd(&h1[wid][f2key(v.z) >> 22], 1u);
        atomicAdd(&h1[wid][f2key(v.w) >> 22], 1u);
    }
    __syncthreads();
    {   // reduce 16 wave-hists -> h2[0..1023]
        unsigned int sum = 0;
        #pragma unroll
        for (int w = 0; w < 16; ++w) sum += h1[w][tid];
        h2[tid] = sum;
    }
    __syncthreads();
    if (tid == 0) {
        unsigned int r = K_SEL;
        int b = 1023;
        for (;; --b) { unsigned int c = h2[b]; if (c >= r) break; r -= c; }
        sh_bin1 = (unsigned int)b; sh_r = r;
    }
    __syncthreads();
    const unsigned int bin1 = sh_bin1;

    // ---- pass 2: bits [21:11] among prefix matches ----
    for (int i = tid; i < 2048; i += 1024) h2[i] = 0u;
    __syncthreads();
    for (int i = tid; i < P4_TOT; i += 1024) {
        float4 v = xs[i];
        unsigned int k;
        k = f2key(v.x); if ((k >> 22) == bin1) atomicAdd(&h2[(k >> 11) & 0x7FFu], 1u);
        k = f2key(v.y); if ((k >> 22) == bin1) atomicAdd(&h2[(k >> 11) & 0x7FFu], 1u);
        k = f2key(v.z); if ((k >> 22) == bin1) atomicAdd(&h2[(k >> 11) & 0x7FFu], 1u);
        k = f2key(v.w); if ((k >> 22) == bin1) atomicAdd(&h2[(k >> 11) & 0x7FFu], 1u);
    }
    __syncthreads();
    if (tid == 0) {
        unsigned int r = sh_r;
        int b = 2047;
        for (;; --b) { unsigned int c = h2[b]; if (c >= r) break; r -= c; }
        sh_bin2 = (unsigned int)b; sh_r = r;
    }
    __syncthreads();
    const unsigned int pre21 = (bin1 << 11) | sh_bin2;

    // ---- pass 3: bits [10:0] among 21-bit prefix matches ----
    for (int i = tid; i < 2048; i += 1024) h2[i] = 0u;
    __syncthreads();
    for (int i = tid; i < P4_TOT; i += 1024) {
        float4 v = xs[i];
        unsigned int k;
        k = f2key(v.x); if ((k >> 11) == pre21) atomicAdd(&h2[k & 0x7FFu], 1u);
        k = f2key(v.y); if ((k >> 11) == pre21) atomicAdd(&h2[k & 0x7FFu], 1u);
        k = f2key(v.z); if ((k >> 11) == pre21) atomicAdd(&h2[k & 0x7FFu], 1u);
        k = f2key(v.w); if ((k >> 11) == pre21) atomicAdd(&h2[k & 0x7FFu], 1u);
    }
    __syncthreads();
    if (tid == 0) {
        unsigned int r = sh_r;
        int b = 2047; unsigned int c;
        for (;; --b) { c = h2[b]; if (c >= r) break; r -= c; }
        sh_bin3 = (unsigned int)b; sh_r = r; sh_ceq = c;
        sh_cnt = 0u;
        sh_cutoff = INT_MAX;   // default: all ties included (needed == ceq)
    }
    __syncthreads();
    const unsigned int T      = (pre21 << 11) | sh_bin3;
    const unsigned int needed = sh_r;      // #ties to include, >= 1
    const unsigned int ceq    = sh_ceq;    // #elements equal to T

    // ---- pass 4 (rare): exact tie cutoff = needed-th smallest index == T ----
    if (needed < ceq) {
        for (int i = tid; i < P4_TOT; i += 1024) {
            float4 v = xs[i];
            unsigned int p;
            if (f2key(v.x) == T) { p = atomicAdd(&sh_cnt, 1u); if (p < 2048u) tiebuf[p] = i*4 + 0; }
            if (f2key(v.y) == T) { p = atomicAdd(&sh_cnt, 1u); if (p < 2048u) tiebuf[p] = i*4 + 1; }
            if (f2key(v.z) == T) { p = atomicAdd(&sh_cnt, 1u); if (p < 2048u) tiebuf[p] = i*4 + 2; }
            if (f2key(v.w) == T) { p = atomicAdd(&sh_cnt, 1u); if (p < 2048u) tiebuf[p] = i*4 + 3; }
        }
        __syncthreads();
        const unsigned int cnt = sh_cnt;   // == ceq
        if (cnt <= 2048u) {
            for (int t = tid; t < (int)cnt; t += 1024) {
                int e = tiebuf[t];
                int rank = 0;
                for (int q = 0; q < (int)cnt; ++q) rank += (tiebuf[q] < e) ? 1 : 0;
                if (rank == (int)needed - 1) sh_cutoff = e;
            }
        } else if (tid == 0) {
            // pathological fallback: sequential ordered scan (never hit for normal data)
            const float* xf = (const float*)xs;
            unsigned int left = needed;
            for (int i = 0; i < P_TOT; ++i)
                if (f2key(xf[i]) == T) { if (--left == 0u) { sh_cutoff = i; break; } }
        }
        __syncthreads();
    }

    if (tid == 0) { info[s].T = T; info[s].cutoff = sh_cutoff; }
}

__device__ __forceinline__ float lif_step(float& u, float xv, unsigned int T, int cutoff, int idx)
{
    // u = TAU*u*(1-spike(u)) + x ; 0.5*u is exact, so bitwise == jax fp32
    u = (u > VTH ? 0.0f : TAU * u) + xv;
    const bool s = u > VTH;
    const unsigned int k = f2key(xv);
    const bool m = (k > T) || ((k == T) && (idx <= cutoff));
    return (s && m) ? 1.0f : 0.0f;
}

__global__ __launch_bounds__(256)
void wta_lif(const float4* __restrict__ x, const SampleInfo* __restrict__ info,
             float4* __restrict__ out)
{
    const int j  = blockIdx.y;                       // 0..31 within time chunk
    const int p4 = blockIdx.x * 256 + threadIdx.x;   // float4 index within sample
    if (p4 >= P4_TOT) return;
    const int idx0 = p4 * 4;

    float4 u = make_float4(0.f, 0.f, 0.f, 0.f);
    #pragma unroll
    for (int t = 0; t < TSTEP; ++t) {
        const int b = t * BS + j;                    // original sample index
        const size_t off = (size_t)b * P4_TOT + p4;
        const float4 xv = x[off];
        const SampleInfo si = info[b];
        float4 o;
        o.x = lif_step(u.x, xv.x, si.T, si.cutoff, idx0 + 0);
        o.y = lif_step(u.y, xv.y, si.T, si.cutoff, idx0 + 1);
        o.z = lif_step(u.z, xv.z, si.T, si.cutoff, idx0 + 2);
        o.w = lif_step(u.w, xv.w, si.T, si.cutoff, idx0 + 3);
        out[off] = o;
    }
}

extern "C" void kernel_launch(void* const* d_in, const int* in_sizes, int n_in,
                              void* d_out, int out_size, void* d_ws, size_t ws_size,
                              hipStream_t stream)
{
    const float4* x = (const float4*)d_in[0];
    SampleInfo* info = (SampleInfo*)d_ws;   // 160 * 8 B

    wta_select<<<dim3(TSTEP * BS), dim3(1024), 0, stream>>>(x, info);
    wta_lif<<<dim3(P4_TOT / 256, BS), dim3(256), 0, stream>>>(x, info, (float4*)d_out);
}